// Round 7
// baseline (115.776 us; speedup 1.0000x reference)
//
#include <hip/hip_runtime.h>

#define NNODES 50000
#define NREL   1000
#define NEDGES 1600000
#define FOUT   64
#define NEG_SLOPE 0.2f

#define SPAN   64                  // dst nodes per bucket (ln fits in 6 bits)
#define NBUCK  782                 // ceil(50000/64)
#define CAP    2560                // records per bucket (mean 2046, sigma 45)
#define CHUNK  4096                // edges per distribute block
#define EPT    16                  // edges per thread
#define DBLK   391                 // ceil(NEDGES/CHUNK)
#define PREB   3188                // ceil((NNODES+NREL)*16/256) score blocks

// record layout: (ln<<26) | (sn<<10) | rn   -- ln<64, sn<65536, rn<1024

// -------- ws layout (bytes, 1 KiB aligned) --------
#define ALIGN1K(x) (((x) + 1023) & ~((size_t)1023))
static const size_t OFF_HS    = 0;                                            // float2[NNODES]
static const size_t OFF_RR    = ALIGN1K(OFF_HS    + sizeof(float2) * NNODES); // float2[NREL]
static const size_t OFF_CNT   = ALIGN1K(OFF_RR    + sizeof(float2) * NREL);   // int[NBUCK] (counts, memset 0)
static const size_t OFF_NR    = ALIGN1K(OFF_CNT   + sizeof(int) * NBUCK);     // int2[NNODES]
static const size_t OFF_STAGE = ALIGN1K(OFF_NR    + sizeof(int2) * NNODES);   // int[NBUCK*CAP]
static const size_t OFF_PERM2 = ALIGN1K(OFF_STAGE + sizeof(int) * NBUCK * CAP); // int[NBUCK*CAP]

// Fused: blocks [0, DBLK) bucket the edges by dst>>6 (chunk reservation on a
// zeroed count array); blocks [DBLK, DBLK+PREB) compute the separable score
// tables hs2[n]=(h[n].a00,(h[n]*w).a10), rr2[r]=(r.a01, r.a11).
__global__ __launch_bounds__(256) void prep_kernel(
    const float* __restrict__ h, const float* __restrict__ inputr,
    const float* __restrict__ w, const float* __restrict__ a_att,
    const int* __restrict__ A, int* __restrict__ ccnt, int* __restrict__ stage,
    float2* __restrict__ hs2, float2* __restrict__ rr2)
{
    const int t = threadIdx.x;
    if (blockIdx.x < DBLK) {
        __shared__ int lcnt[NBUCK];
        __shared__ int gbase[NBUCK];
        for (int i = t; i < NBUCK; i += 256) lcnt[i] = 0;
        __syncthreads();

        const int base = blockIdx.x * CHUNK;
        int rec[EPT];
        int bkt[EPT];
        int off[EPT];

        #pragma unroll
        for (int k = 0; k < EPT; k++) {
            const int e = base + k * 256 + t;
            if (e < NEDGES) {
                const int dn = __builtin_nontemporal_load(A + e);
                const int rn = __builtin_nontemporal_load(A + NEDGES + e);
                const int sn = __builtin_nontemporal_load(A + 2 * NEDGES + e);
                const int b  = dn >> 6;
                rec[k] = ((dn & 63) << 26) | (sn << 10) | rn;
                bkt[k] = b;
                off[k] = atomicAdd(&lcnt[b], 1);
            } else {
                off[k] = -1;
            }
        }
        __syncthreads();

        for (int i = t; i < NBUCK; i += 256) {
            const int c = lcnt[i];
            if (c > 0) gbase[i] = i * CAP + atomicAdd(&ccnt[i], c);
        }
        __syncthreads();

        #pragma unroll
        for (int k = 0; k < EPT; k++) {
            if (off[k] >= 0) {
                const int pos = gbase[bkt[k]] + off[k];
                if (pos < (bkt[k] + 1) * CAP)   // safety clamp (cannot trigger)
                    stage[pos] = rec[k];
            }
        }
        return;
    }

    // ---- score table part ----
    const int lane = t & 15;
    const int f0   = lane << 2;
    const int g    = (blockIdx.x - DBLK) * 16 + (t >> 4);
    if (g >= NNODES + NREL) return;

    const float4 a00 = *(const float4*)(a_att +   0 + f0);
    const float4 a01 = *(const float4*)(a_att +  64 + f0);
    const float4 a10 = *(const float4*)(a_att + 128 + f0);
    const float4 a11 = *(const float4*)(a_att + 192 + f0);
    const float4 wv  = *(const float4*)(w + f0);

    float p0, p1;
    if (g < NNODES) {
        const float4 v = *(const float4*)(h + (size_t)g * FOUT + f0);
        p0 = v.x * a00.x + v.y * a00.y + v.z * a00.z + v.w * a00.w;
        p1 = v.x * wv.x * a10.x + v.y * wv.y * a10.y
           + v.z * wv.z * a10.z + v.w * wv.w * a10.w;
    } else {
        const float4 v = *(const float4*)(inputr + (size_t)(g - NNODES) * FOUT + f0);
        p0 = v.x * a01.x + v.y * a01.y + v.z * a01.z + v.w * a01.w;
        p1 = v.x * a11.x + v.y * a11.y + v.z * a11.z + v.w * a11.w;
    }
    #pragma unroll
    for (int off = 8; off >= 1; off >>= 1) {
        p0 += __shfl_xor(p0, off, 16);
        p1 += __shfl_xor(p1, off, 16);
    }
    if (lane == 0) {
        if (g < NNODES) hs2[g] = make_float2(p0, p1);
        else            rr2[g - NNODES] = make_float2(p0, p1);
    }
}

// One block per bucket: LDS histogram over 64 local nodes, wave-0 shuffle
// scan, then in-bucket scatter (stays in one XCD's L2). Emits nrange per node.
__global__ __launch_bounds__(256) void sort_kernel(
    const int* __restrict__ stage, const int* __restrict__ ccnt,
    int* __restrict__ perm2, int2* __restrict__ nrange)
{
    __shared__ int hist[SPAN];
    __shared__ int offs[SPAN];
    const int b = blockIdx.x;
    const int t = threadIdx.x;
    int cnt = ccnt[b];
    if (cnt > CAP) cnt = CAP;
    const int base = b * CAP;

    if (t < SPAN) hist[t] = 0;
    __syncthreads();

    for (int i = t; i < cnt; i += 256)
        atomicAdd(&hist[((unsigned)stage[base + i]) >> 26], 1);
    __syncthreads();

    if (t < SPAN) {   // wave 0: inclusive shuffle scan over 64 counters
        const int c = hist[t];
        int v = c;
        #pragma unroll
        for (int d = 1; d < 64; d <<= 1) {
            const int u = __shfl_up(v, d);
            if (t >= d) v += u;
        }
        const int excl = v - c;
        offs[t] = excl;
        const int node = b * SPAN + t;
        if (node < NNODES)
            nrange[node] = make_int2(base + excl, base + excl + c);
    }
    __syncthreads();

    for (int i = t; i < cnt; i += 256) {
        const int rec = stage[base + i];
        const int pos = base + atomicAdd(&offs[((unsigned)rec) >> 26], 1);
        perm2[pos] = rec;
    }
}

// One wave per dst node; 4 x 16-lane quarters each own one edge; each lane
// owns a float4 of the 64 features. Unrolled 2x: each quarter processes edges
// i and i+4 per iteration -> ~10 independent loads in flight.
__global__ __launch_bounds__(256) void aggregate_kernel(
    const float* __restrict__ h, const float* __restrict__ inputr,
    const float* __restrict__ w,
    const int* __restrict__ perm2, const int2* __restrict__ nrange,
    const float2* __restrict__ hs2, const float2* __restrict__ rr2,
    float* __restrict__ out)
{
    const int wid  = (blockIdx.x * blockDim.x + threadIdx.x) >> 6;  // node id
    const int lane = threadIdx.x & 63;
    const int q    = lane >> 4;        // quarter: which edge of a group of 4
    const int f4   = (lane & 15) << 2; // feature base (float4)
    if (wid >= NNODES) return;

    const int2 nr = nrange[wid];
    const int b = nr.x, e = nr.y;
    const float4 wl = *(const float4*)(w + f4);

    float4 acc0 = make_float4(0.f, 0.f, 0.f, 0.f);
    float4 acc1 = make_float4(0.f, 0.f, 0.f, 0.f);
    float sum0 = 0.f, sum1 = 0.f;

    int i = b + q;
    // main loop: two edges per quarter per iteration
    for (; i + 4 < e; i += 8) {
        const int pa = perm2[i];
        const int pb = perm2[i + 4];
        const int sna = (pa >> 10) & 0xFFFF, rna = pa & 1023;
        const int snb = (pb >> 10) & 0xFFFF, rnb = pb & 1023;

        const float2 hva = hs2[sna];
        const float2 rva = rr2[rna];
        const float2 hvb = hs2[snb];
        const float2 rvb = rr2[rnb];
        const float4 sa = *(const float4*)(h      + (size_t)sna * FOUT + f4);
        const float4 ra = *(const float4*)(inputr + (size_t)rna * FOUT + f4);
        const float4 sb = *(const float4*)(h      + (size_t)snb * FOUT + f4);
        const float4 rb = *(const float4*)(inputr + (size_t)rnb * FOUT + f4);

        const float sa0 = hva.x + rva.x, sa1 = hva.y + rva.y;
        const float sb0 = hvb.x + rvb.x, sb1 = hvb.y + rvb.y;
        const float ea0 = __expf(-fmaxf(sa0, NEG_SLOPE * sa0));
        const float ea1 = __expf(-fmaxf(sa1, NEG_SLOPE * sa1));
        const float eb0 = __expf(-fmaxf(sb0, NEG_SLOPE * sb0));
        const float eb1 = __expf(-fmaxf(sb1, NEG_SLOPE * sb1));

        acc0.x += (sa.x - ra.x) * ea0 + (sb.x - rb.x) * eb0;
        acc0.y += (sa.y - ra.y) * ea0 + (sb.y - rb.y) * eb0;
        acc0.z += (sa.z - ra.z) * ea0 + (sb.z - rb.z) * eb0;
        acc0.w += (sa.w - ra.w) * ea0 + (sb.w - rb.w) * eb0;
        acc1.x += fmaf(sa.x, wl.x, -ra.x) * ea1 + fmaf(sb.x, wl.x, -rb.x) * eb1;
        acc1.y += fmaf(sa.y, wl.y, -ra.y) * ea1 + fmaf(sb.y, wl.y, -rb.y) * eb1;
        acc1.z += fmaf(sa.z, wl.z, -ra.z) * ea1 + fmaf(sb.z, wl.z, -rb.z) * eb1;
        acc1.w += fmaf(sa.w, wl.w, -ra.w) * ea1 + fmaf(sb.w, wl.w, -rb.w) * eb1;
        sum0 += ea0 + eb0;
        sum1 += ea1 + eb1;
    }
    if (i < e) {   // at most one leftover edge per quarter
        const int p  = perm2[i];
        const int sn = (p >> 10) & 0xFFFF, rn = p & 1023;
        const float2 hv = hs2[sn];
        const float2 rv = rr2[rn];
        const float4 s = *(const float4*)(h      + (size_t)sn * FOUT + f4);
        const float4 r = *(const float4*)(inputr + (size_t)rn * FOUT + f4);
        const float sc0 = hv.x + rv.x, sc1 = hv.y + rv.y;
        const float e0 = __expf(-fmaxf(sc0, NEG_SLOPE * sc0));
        const float e1 = __expf(-fmaxf(sc1, NEG_SLOPE * sc1));
        acc0.x += (s.x - r.x) * e0;
        acc0.y += (s.y - r.y) * e0;
        acc0.z += (s.z - r.z) * e0;
        acc0.w += (s.w - r.w) * e0;
        acc1.x += fmaf(s.x, wl.x, -r.x) * e1;
        acc1.y += fmaf(s.y, wl.y, -r.y) * e1;
        acc1.z += fmaf(s.z, wl.z, -r.z) * e1;
        acc1.w += fmaf(s.w, wl.w, -r.w) * e1;
        sum0 += e0;
        sum1 += e1;
    }

    // Combine the 4 quarters: xor-16 then xor-32 swap-adds.
    #pragma unroll
    for (int off = 16; off <= 32; off <<= 1) {
        acc0.x += __shfl_xor(acc0.x, off);
        acc0.y += __shfl_xor(acc0.y, off);
        acc0.z += __shfl_xor(acc0.z, off);
        acc0.w += __shfl_xor(acc0.w, off);
        acc1.x += __shfl_xor(acc1.x, off);
        acc1.y += __shfl_xor(acc1.y, off);
        acc1.z += __shfl_xor(acc1.z, off);
        acc1.w += __shfl_xor(acc1.w, off);
        sum0   += __shfl_xor(sum0, off);
        sum1   += __shfl_xor(sum1, off);
    }

    if (q == 0) {
        const float inv = 1.0f / sum0;
        float4 o = make_float4(acc0.x * inv, acc0.y * inv, acc0.z * inv, acc0.w * inv);
        *(float4*)(out + (size_t)wid * FOUT + f4) = o;
    } else if (q == 1) {
        const float inv = 1.0f / sum1;
        float4 o = make_float4(acc1.x * inv, acc1.y * inv, acc1.z * inv, acc1.w * inv);
        *(float4*)(out + ((size_t)NNODES + wid) * FOUT + f4) = o;
    }
}

extern "C" void kernel_launch(void* const* d_in, const int* in_sizes, int n_in,
                              void* d_out, int out_size, void* d_ws, size_t ws_size,
                              hipStream_t stream) {
    const float* h      = (const float*)d_in[0];
    const float* inputr = (const float*)d_in[1];
    const int*   A      = (const int*)d_in[2];
    const float* w      = (const float*)d_in[3];
    const float* a_att  = (const float*)d_in[4];

    char* ws = (char*)d_ws;
    float2* hs2    = (float2*)(ws + OFF_HS);
    float2* rr2    = (float2*)(ws + OFF_RR);
    int*    ccnt   = (int*)(ws + OFF_CNT);
    int2*   nrange = (int2*)(ws + OFF_NR);
    int*    stage  = (int*)(ws + OFF_STAGE);
    int*    perm2  = (int*)(ws + OFF_PERM2);
    float*  out    = (float*)d_out;

    // Bucket counters -> 0 (cheap memset node; keeps prep fusion race-free).
    hipMemsetAsync(ccnt, 0, sizeof(int) * NBUCK, stream);

    // 1. Fused: edge bucketing + score tables.
    prep_kernel<<<dim3(DBLK + PREB), dim3(256), 0, stream>>>(
        h, inputr, w, a_att, A, ccnt, stage, hs2, rr2);
    // 2. Per-bucket counting sort -> exact CSR (perm2, nrange).
    sort_kernel<<<dim3(NBUCK), dim3(256), 0, stream>>>(stage, ccnt, perm2, nrange);
    // 3. One wave per dst node, 8 edges per iteration (2 per quarter).
    aggregate_kernel<<<dim3((NNODES * 64) / 256), dim3(256), 0, stream>>>(
        h, inputr, w, perm2, nrange, hs2, rr2, out);
}